// Round 1
// baseline (165.052 us; speedup 1.0000x reference)
//
#include <hip/hip_runtime.h>

static constexpr int B = 16, C = 64, H = 256, W = 256;
static constexpr int HW = H * W;              // 65536
static constexpr int KS = 7, PAD = 3;

// ---------------- Kernel 1: channel-wise mean & max ----------------
// One thread per 4 consecutive pixels (float4). Loop over 64 channels,
// stride HW floats; every iteration is a fully coalesced wave read.
__global__ void __launch_bounds__(256) reduce_mean_max(
    const float* __restrict__ x, float* __restrict__ avg, float* __restrict__ mx)
{
    int idx = blockIdx.x * 256 + threadIdx.x;     // over B*HW/4 = 262144
    int b   = idx >> 14;                          // HW/4 = 16384 = 2^14
    const float4* xp = reinterpret_cast<const float4*>(x)
                     + (size_t)b * (C * (HW / 4)) + (idx & (HW / 4 - 1));
    float4 v = xp[0];
    float sx = v.x, sy = v.y, sz = v.z, sw = v.w;
    float ax = v.x, ay = v.y, az = v.z, aw = v.w;
    #pragma unroll 8
    for (int c = 1; c < C; ++c) {
        float4 t = xp[(size_t)c * (HW / 4)];
        sx += t.x; sy += t.y; sz += t.z; sw += t.w;
        ax = fmaxf(ax, t.x); ay = fmaxf(ay, t.y);
        az = fmaxf(az, t.z); aw = fmaxf(aw, t.w);
    }
    const float inv = 1.0f / C;
    reinterpret_cast<float4*>(avg)[idx] = make_float4(sx*inv, sy*inv, sz*inv, sw*inv);
    reinterpret_cast<float4*>(mx)[idx]  = make_float4(ax, ay, az, aw);
}

// ---------------- Kernel 2: 7x7 conv (2->1) + bias + sigmoid ----------------
// 16x16 output tile per 256-thread block; 22x22 input halo staged in LDS
// with row stride 24 (2-way bank aliasing only -> free).
__global__ void __launch_bounds__(256) conv_sigmoid(
    const float* __restrict__ avg, const float* __restrict__ mx,
    const float* __restrict__ wgt, const float* __restrict__ bias,
    float* __restrict__ mask)
{
    constexpr int TS = 16;
    constexpr int TI = TS + KS - 1;   // 22
    __shared__ float sa[TI][24];
    __shared__ float sm[TI][24];

    const int tx = threadIdx.x & 15;
    const int ty = threadIdx.x >> 4;
    const int w0 = blockIdx.x * TS;
    const int h0 = blockIdx.y * TS;
    const int b  = blockIdx.z;

    const float* ap = avg + (size_t)b * HW;
    const float* mp = mx  + (size_t)b * HW;

    for (int e = threadIdx.x; e < TI * TI; e += 256) {
        int r = e / TI, c = e % TI;
        int gh = h0 + r - PAD, gw = w0 + c - PAD;
        bool ok = ((unsigned)gh < (unsigned)H) && ((unsigned)gw < (unsigned)W);
        int gi = gh * W + gw;
        sa[r][c] = ok ? ap[gi] : 0.0f;
        sm[r][c] = ok ? mp[gi] : 0.0f;
    }
    __syncthreads();

    float acc = bias[0];
    #pragma unroll
    for (int ky = 0; ky < KS; ++ky) {
        #pragma unroll
        for (int kx = 0; kx < KS; ++kx) {
            acc += sa[ty + ky][tx + kx] * wgt[ky * KS + kx];         // avg channel
            acc += sm[ty + ky][tx + kx] * wgt[49 + ky * KS + kx];    // max channel
        }
    }
    float s = 1.0f / (1.0f + expf(-acc));
    mask[(size_t)b * HW + (h0 + ty) * W + (w0 + tx)] = s;
}

// ---------------- Kernel 3: out = x * mask (broadcast over C) ----------------
__global__ void __launch_bounds__(256) apply_mask(
    const float* __restrict__ x, const float* __restrict__ mask,
    float* __restrict__ out)
{
    int idx = blockIdx.x * 256 + threadIdx.x;     // over B*C*HW/4 = 16777216
    int b   = idx >> 20;                          // C*HW/4 = 2^20
    int hw4 = idx & (HW / 4 - 1);
    float4 xv = reinterpret_cast<const float4*>(x)[idx];
    float4 mv = reinterpret_cast<const float4*>(mask)[(b << 14) + hw4];
    reinterpret_cast<float4*>(out)[idx] =
        make_float4(xv.x * mv.x, xv.y * mv.y, xv.z * mv.z, xv.w * mv.w);
}

extern "C" void kernel_launch(void* const* d_in, const int* in_sizes, int n_in,
                              void* d_out, int out_size, void* d_ws, size_t ws_size,
                              hipStream_t stream) {
    const float* x      = (const float*)d_in[0];
    const float* conv_w = (const float*)d_in[1];   // [1,2,7,7] OIHW flat
    const float* conv_b = (const float*)d_in[2];   // [1]
    float* out  = (float*)d_out;

    float* avg  = (float*)d_ws;                    // B*HW floats = 4 MiB
    float* mx   = avg + (size_t)B * HW;            // 4 MiB
    float* mask = mx  + (size_t)B * HW;            // 4 MiB

    reduce_mean_max<<<(B * HW / 4) / 256, 256, 0, stream>>>(x, avg, mx);

    dim3 cgrid(W / 16, H / 16, B);
    conv_sigmoid<<<cgrid, 256, 0, stream>>>(avg, mx, conv_w, conv_b, mask);

    apply_mask<<<(B * C * HW / 4) / 256, 256, 0, stream>>>(x, mask, out);
}

// Round 2
// 143.012 us; speedup vs baseline: 1.1541x; 1.1541x over previous
//
#include <hip/hip_runtime.h>

static constexpr int B = 16, C = 64, H = 256, W = 256;
static constexpr int HW = H * W;              // 65536
static constexpr int KS = 7, PAD = 3;

typedef float f4 __attribute__((ext_vector_type(4)));

// ---------------- Kernel 1: channel-wise mean & max ----------------
// One thread per 4 consecutive pixels (float4). Loop over 64 channels,
// stride HW floats; every iteration is a fully coalesced wave read.
// Regular (caching) loads: we WANT x to land in L3 so kernel 3 hits it.
__global__ void __launch_bounds__(256) reduce_mean_max(
    const float* __restrict__ x, float* __restrict__ avg, float* __restrict__ mx)
{
    int idx = blockIdx.x * 256 + threadIdx.x;     // over B*HW/4 = 262144
    int b   = idx >> 14;                          // HW/4 = 16384 = 2^14
    const f4* xp = reinterpret_cast<const f4*>(x)
                 + (size_t)b * (C * (HW / 4)) + (idx & (HW / 4 - 1));
    f4 v = xp[0];
    f4 s = v;
    f4 a = v;
    #pragma unroll 8
    for (int c = 1; c < C; ++c) {
        f4 t = xp[(size_t)c * (HW / 4)];
        s += t;
        a.x = fmaxf(a.x, t.x); a.y = fmaxf(a.y, t.y);
        a.z = fmaxf(a.z, t.z); a.w = fmaxf(a.w, t.w);
    }
    const float inv = 1.0f / C;
    reinterpret_cast<f4*>(avg)[idx] = s * inv;
    reinterpret_cast<f4*>(mx)[idx]  = a;
}

// ---------------- Kernel 2: 7x7 conv (2->1) + bias + sigmoid ----------------
// 16x16 output tile per 256-thread block; 22x22 input halo staged in LDS
// with row stride 24 (2-way bank aliasing only -> free).
__global__ void __launch_bounds__(256) conv_sigmoid(
    const float* __restrict__ avg, const float* __restrict__ mx,
    const float* __restrict__ wgt, const float* __restrict__ bias,
    float* __restrict__ mask)
{
    constexpr int TS = 16;
    constexpr int TI = TS + KS - 1;   // 22
    __shared__ float sa[TI][24];
    __shared__ float sm[TI][24];

    const int tx = threadIdx.x & 15;
    const int ty = threadIdx.x >> 4;
    const int w0 = blockIdx.x * TS;
    const int h0 = blockIdx.y * TS;
    const int b  = blockIdx.z;

    const float* ap = avg + (size_t)b * HW;
    const float* mp = mx  + (size_t)b * HW;

    for (int e = threadIdx.x; e < TI * TI; e += 256) {
        int r = e / TI, c = e % TI;
        int gh = h0 + r - PAD, gw = w0 + c - PAD;
        bool ok = ((unsigned)gh < (unsigned)H) && ((unsigned)gw < (unsigned)W);
        int gi = gh * W + gw;
        sa[r][c] = ok ? ap[gi] : 0.0f;
        sm[r][c] = ok ? mp[gi] : 0.0f;
    }
    __syncthreads();

    float acc = bias[0];
    #pragma unroll
    for (int ky = 0; ky < KS; ++ky) {
        #pragma unroll
        for (int kx = 0; kx < KS; ++kx) {
            acc += sa[ty + ky][tx + kx] * wgt[ky * KS + kx];         // avg channel
            acc += sm[ty + ky][tx + kx] * wgt[49 + ky * KS + kx];    // max channel
        }
    }
    float s = 1.0f / (1.0f + expf(-acc));
    mask[(size_t)b * HW + (h0 + ty) * W + (w0 + tx)] = s;
}

// ---------------- Kernel 3: out = x * mask (broadcast over C) ----------------
// x read: regular (should hit L3 after kernel 1 streamed it).
// out store: NON-TEMPORAL -> don't evict x from L3; out is never re-read.
__global__ void __launch_bounds__(256) apply_mask(
    const float* __restrict__ x, const float* __restrict__ mask,
    float* __restrict__ out)
{
    int idx = blockIdx.x * 256 + threadIdx.x;     // over B*C*HW/4 = 16777216
    int b   = idx >> 20;                          // C*HW/4 = 2^20
    int hw4 = idx & (HW / 4 - 1);
    f4 xv = reinterpret_cast<const f4*>(x)[idx];
    f4 mv = reinterpret_cast<const f4*>(mask)[(b << 14) + hw4];
    f4 r  = xv * mv;
    __builtin_nontemporal_store(r, reinterpret_cast<f4*>(out) + idx);
}

extern "C" void kernel_launch(void* const* d_in, const int* in_sizes, int n_in,
                              void* d_out, int out_size, void* d_ws, size_t ws_size,
                              hipStream_t stream) {
    const float* x      = (const float*)d_in[0];
    const float* conv_w = (const float*)d_in[1];   // [1,2,7,7] OIHW flat
    const float* conv_b = (const float*)d_in[2];   // [1]
    float* out  = (float*)d_out;

    float* avg  = (float*)d_ws;                    // B*HW floats = 4 MiB
    float* mx   = avg + (size_t)B * HW;            // 4 MiB
    float* mask = mx  + (size_t)B * HW;            // 4 MiB

    reduce_mean_max<<<(B * HW / 4) / 256, 256, 0, stream>>>(x, avg, mx);

    dim3 cgrid(W / 16, H / 16, B);
    conv_sigmoid<<<cgrid, 256, 0, stream>>>(avg, mx, conv_w, conv_b, mask);

    apply_mask<<<(B * C * HW / 4) / 256, 256, 0, stream>>>(x, mask, out);
}